// Round 10
// baseline (729.578 us; speedup 1.0000x reference)
//
#include <hip/hip_runtime.h>
#include <math.h>

#define N_NODES 100000
#define N_EDGES 640000
#define IN_DIM 64
#define HID 128
#define NGRAPH 128

typedef __bf16 bf16x2 __attribute__((ext_vector_type(2)));
typedef __bf16 bf16x4 __attribute__((ext_vector_type(4)));
typedef __bf16 bf16x8 __attribute__((ext_vector_type(8)));
typedef float f32x4 __attribute__((ext_vector_type(4)));

#define LDST 136  // bf16 elements per LDS row: 272 B, 16B-aligned, breaks pow2 stride
#define KCAT 384  // LSTM concat K: 256 (q_star) + 128 (h_l)
#define KPAD 392  // padded LDS row for gates kernel (784 B, 16B-aligned)

// fast transcendentals; inf-safe at both ends.
__device__ __forceinline__ float sigmoid_f(float z) {
  return __fdividef(1.f, 1.f + __expf(-z));
}
__device__ __forceinline__ float tanh_f(float z) {
  return 1.f - __fdividef(2.f, __expf(2.f * z) + 1.f);
}

// ---------------------------------------------------------------------------
// fma helper (used by k_input only)
// ---------------------------------------------------------------------------
__device__ __forceinline__ void fma44(const float4 A[4], const float4 B[4], float acc[4][4]) {
#pragma unroll
  for (int i2 = 0; i2 < 4; ++i2) {
    acc[i2][0] += A[i2].x*B[0].x + A[i2].y*B[1].x + A[i2].z*B[2].x + A[i2].w*B[3].x;
    acc[i2][1] += A[i2].x*B[0].y + A[i2].y*B[1].y + A[i2].z*B[2].y + A[i2].w*B[3].y;
    acc[i2][2] += A[i2].x*B[0].z + A[i2].y*B[1].z + A[i2].z*B[2].z + A[i2].w*B[3].z;
    acc[i2][3] += A[i2].x*B[0].w + A[i2].y*B[1].w + A[i2].z*B[2].w + A[i2].w*B[3].w;
  }
}

// ---------------------------------------------------------------------------
// Kernel 1: h = relu(x @ W_in.T + b_in)
// ---------------------------------------------------------------------------
__global__ __launch_bounds__(256) void k_input(const float* __restrict__ x,
                                               const float* __restrict__ W,
                                               const float* __restrict__ b,
                                               float* __restrict__ h) {
  __shared__ float wS[64][132];
  __shared__ float xS[32][68];
  int t = threadIdx.x;
  int nb = blockIdx.x * 32;
#pragma unroll
  for (int i = 0; i < 8; ++i) {
    int idx4 = i * 256 + t;
    int j = idx4 >> 4, kq = idx4 & 15;
    float4 v = ((const float4*)W)[j * 16 + kq];
    wS[4*kq+0][j] = v.x; wS[4*kq+1][j] = v.y; wS[4*kq+2][j] = v.z; wS[4*kq+3][j] = v.w;
  }
#pragma unroll
  for (int i = 0; i < 2; ++i) {
    int idx4 = i * 256 + t;
    int n = idx4 >> 4, kq = idx4 & 15;
    float4 v = ((const float4*)x)[(nb + n) * 16 + kq];
    *((float4*)&xS[n][4*kq]) = v;
  }
  __syncthreads();
  int bq = t & 31, a = t >> 5;
  float acc[4][4] = {};
#pragma unroll
  for (int kk4 = 0; kk4 < 16; ++kk4) {
    float4 A[4], B[4];
#pragma unroll
    for (int i2 = 0; i2 < 4; ++i2) A[i2] = *((const float4*)&xS[4*a+i2][4*kk4]);
#pragma unroll
    for (int c = 0; c < 4; ++c) B[c] = *((const float4*)&wS[4*kk4+c][4*bq]);
    fma44(A, B, acc);
  }
  float4 bb = ((const float4*)b)[bq];
  float ba[4] = {bb.x, bb.y, bb.z, bb.w};
#pragma unroll
  for (int i2 = 0; i2 < 4; ++i2) {
    float4 o;
    o.x = fmaxf(acc[i2][0] + ba[0], 0.f);
    o.y = fmaxf(acc[i2][1] + ba[1], 0.f);
    o.z = fmaxf(acc[i2][2] + ba[2], 0.f);
    o.w = fmaxf(acc[i2][3] + ba[3], 0.f);
    ((float4*)h)[(nb + 4*a + i2) * 32 + bq] = o;
  }
}

// ---------------------------------------------------------------------------
// CSR build: histogram -> scan -> fill
// ---------------------------------------------------------------------------
__global__ __launch_bounds__(256) void k_hist(const int* __restrict__ dst,
                                              int* __restrict__ deg) {
  int e = blockIdx.x * 256 + threadIdx.x;
  if (e < N_EDGES) atomicAdd(&deg[dst[e]], 1);
}

#define SCAN_CHUNK 4096
#define SCAN_NB 25

__global__ __launch_bounds__(256) void k_scan_part(const int* __restrict__ deg,
                                                   int* __restrict__ bsum) {
  __shared__ int red[256];
  int t = threadIdx.x, b = blockIdx.x;
  int base = b * SCAN_CHUNK + t * 16;
  int s = 0;
#pragma unroll
  for (int i = 0; i < 16; ++i) {
    int idx = base + i;
    if (idx < N_NODES) s += deg[idx];
  }
  red[t] = s;
  __syncthreads();
  for (int off = 128; off > 0; off >>= 1) {
    if (t < off) red[t] += red[t + off];
    __syncthreads();
  }
  if (t == 0) bsum[b] = red[0];
}

__global__ void k_scan_mid(const int* __restrict__ bsum, int* __restrict__ boff,
                           int* __restrict__ rowstart) {
  if (threadIdx.x == 0) {
    int run = 0;
    for (int i = 0; i < SCAN_NB; ++i) { boff[i] = run; run += bsum[i]; }
    rowstart[N_NODES] = run;
  }
}

__global__ __launch_bounds__(256) void k_scan_final(const int* __restrict__ deg,
                                                    const int* __restrict__ boff,
                                                    int* __restrict__ rowstart) {
  __shared__ int ts[256];
  int t = threadIdx.x, b = blockIdx.x;
  int base = b * SCAN_CHUNK + t * 16;
  int v[16];
  int s = 0;
#pragma unroll
  for (int i = 0; i < 16; ++i) {
    int idx = base + i;
    v[i] = (idx < N_NODES) ? deg[idx] : 0;
    s += v[i];
  }
  ts[t] = s;
  __syncthreads();
  for (int off = 1; off < 256; off <<= 1) {
    int add = (t >= off) ? ts[t - off] : 0;
    __syncthreads();
    ts[t] += add;
    __syncthreads();
  }
  int run = boff[b] + ts[t] - s;
#pragma unroll
  for (int i = 0; i < 16; ++i) {
    int idx = base + i;
    if (idx < N_NODES) rowstart[idx] = run;
    run += v[i];
  }
}

__global__ __launch_bounds__(256) void k_fill(const int* __restrict__ src,
                                              const int* __restrict__ dst,
                                              int* __restrict__ cursor,
                                              int* __restrict__ srcSorted) {
  int e = blockIdx.x * 256 + threadIdx.x;
  if (e >= N_EDGES) return;
  int d = dst[e];
  int p = atomicAdd(&cursor[d], 1);
  srcSorted[p] = src[e];
}

// ---------------------------------------------------------------------------
// One-time weight split fp32 -> bf16 (hi, lo). Layout preserved: [mat][j][k]
// ---------------------------------------------------------------------------
__global__ __launch_bounds__(256) void k_wsplit(const float* __restrict__ W0,
                                                const float* __restrict__ W1,
                                                const float* __restrict__ W2,
                                                const float* __restrict__ W3,
                                                __bf16* __restrict__ Whi,
                                                __bf16* __restrict__ Wlo) {
  int id = blockIdx.x * 256 + threadIdx.x;  // 65536 total
  int mat = id >> 14, idx = id & 16383;
  const float* W = (mat == 0) ? W0 : (mat == 1) ? W1 : (mat == 2) ? W2 : W3;
  float v = W[idx];
  __bf16 hi = (__bf16)v;
  Whi[id] = hi;
  Wlo[id] = (__bf16)(v - (float)hi);
}

// One-time LSTM weight concat+split: Wcat[j][0..255]=w_ih[j], [256..383]=w_hh[j]
__global__ void k_wsplit2(const float* __restrict__ w_ih,
                          const float* __restrict__ w_hh,
                          __bf16* __restrict__ WcHi,
                          __bf16* __restrict__ WcLo) {
  int j = blockIdx.x;   // 512
  int k = threadIdx.x;  // 384
  float v = (k < 256) ? w_ih[j * 256 + k] : w_hh[j * 128 + (k - 256)];
  __bf16 hi = (__bf16)v;
  WcHi[j * KCAT + k] = hi;
  WcLo[j * KCAT + k] = (__bf16)(v - (float)hi);
}

// ---------------------------------------------------------------------------
// Aggregation (gather): m[n] = sum_{j in CSR[n]} h[srcSorted[j]]
// ---------------------------------------------------------------------------
__global__ __launch_bounds__(256) void k_gather(const float* __restrict__ h,
                                                const int* __restrict__ rowstart,
                                                const int* __restrict__ srcSorted,
                                                float* __restrict__ m) {
  int node = blockIdx.x * 8 + (threadIdx.x >> 5);
  if (node >= N_NODES) return;
  int li = threadIdx.x & 31;
  int j0 = rowstart[node], j1 = rowstart[node + 1];
  const float4* h4 = (const float4*)h;
  float4 a0 = {0.f, 0.f, 0.f, 0.f}, a1 = {0.f, 0.f, 0.f, 0.f};
  int j = j0;
  for (; j + 1 < j1; j += 2) {
    int s0 = srcSorted[j], s1 = srcSorted[j + 1];
    float4 v0 = h4[s0 * 32 + li];
    float4 v1 = h4[s1 * 32 + li];
    a0.x += v0.x; a0.y += v0.y; a0.z += v0.z; a0.w += v0.w;
    a1.x += v1.x; a1.y += v1.y; a1.z += v1.z; a1.w += v1.w;
  }
  if (j < j1) {
    int s0 = srcSorted[j];
    float4 v0 = h4[s0 * 32 + li];
    a0.x += v0.x; a0.y += v0.y; a0.z += v0.z; a0.w += v0.w;
  }
  float4 o = {a0.x + a1.x, a0.y + a1.y, a0.z + a1.z, a0.w + a1.w};
  ((float4*)m)[node * 32 + li] = o;
}

// ---------------------------------------------------------------------------
// Fused MGU update, MFMA split-bf16, in-place on h. (R9 version, unchanged)
// ---------------------------------------------------------------------------
__global__ __launch_bounds__(256) void k_mgu(float* __restrict__ h,
                                             const float* __restrict__ m,
                                             const __bf16* __restrict__ Whi,
                                             const __bf16* __restrict__ Wlo,
                                             const float* __restrict__ bfp,
                                             const float* __restrict__ bhp) {
  __shared__ __bf16 mHi[64 * LDST], mLo[64 * LDST];
  __shared__ __bf16 hHi[64 * LDST], hLo[64 * LDST];  // becomes g after f-gate
  const int t = threadIdx.x;
  const int nb = blockIdx.x * 64;

#pragma unroll
  for (int i = 0; i < 8; ++i) {
    int idx4 = i * 256 + t;
    int n = idx4 >> 5, kq = idx4 & 31;
    float4 vm = ((const float4*)m)[(nb + n) * 32 + kq];
    float4 vh = ((const float4*)h)[(nb + n) * 32 + kq];
    bf16x4 mh, ml, hh, hl;
    mh[0] = (__bf16)vm.x; ml[0] = (__bf16)(vm.x - (float)mh[0]);
    mh[1] = (__bf16)vm.y; ml[1] = (__bf16)(vm.y - (float)mh[1]);
    mh[2] = (__bf16)vm.z; ml[2] = (__bf16)(vm.z - (float)mh[2]);
    mh[3] = (__bf16)vm.w; ml[3] = (__bf16)(vm.w - (float)mh[3]);
    hh[0] = (__bf16)vh.x; hl[0] = (__bf16)(vh.x - (float)hh[0]);
    hh[1] = (__bf16)vh.y; hl[1] = (__bf16)(vh.y - (float)hh[1]);
    hh[2] = (__bf16)vh.z; hl[2] = (__bf16)(vh.z - (float)hh[2]);
    hh[3] = (__bf16)vh.w; hl[3] = (__bf16)(vh.w - (float)hh[3]);
    int e0 = n * LDST + 4 * kq;
    *(bf16x4*)&mHi[e0] = mh; *(bf16x4*)&mLo[e0] = ml;
    *(bf16x4*)&hHi[e0] = hh; *(bf16x4*)&hLo[e0] = hl;
  }
  __syncthreads();

  const int w = t >> 6, l = t & 63;
  const int lj = l & 15, q = l >> 4;

  float bfj[2], bhj[2];
#pragma unroll
  for (int ct = 0; ct < 2; ++ct) {
    int j = (2 * w + ct) * 16 + lj;
    bfj[ct] = bfp[j];
    bhj[ct] = bhp[j];
  }

  f32x4 acc[4][2] = {};

#pragma unroll
  for (int kc = 0; kc < 128; kc += 32) {
    bf16x8 bwh[2], bwl[2], buh[2], bul[2];
#pragma unroll
    for (int ct = 0; ct < 2; ++ct) {
      int off = ((2 * w + ct) * 16 + lj) * 128 + kc + q * 8;
      bwh[ct] = *(const bf16x8*)&Whi[off];
      bwl[ct] = *(const bf16x8*)&Wlo[off];
      buh[ct] = *(const bf16x8*)&Whi[16384 + off];
      bul[ct] = *(const bf16x8*)&Wlo[16384 + off];
    }
#pragma unroll
    for (int rt = 0; rt < 4; ++rt) {
      int e0 = (rt * 16 + lj) * LDST + kc + q * 8;
      bf16x8 amh = *(const bf16x8*)&mHi[e0];
      bf16x8 aml = *(const bf16x8*)&mLo[e0];
      bf16x8 ahh = *(const bf16x8*)&hHi[e0];
      bf16x8 ahl = *(const bf16x8*)&hLo[e0];
#pragma unroll
      for (int ct = 0; ct < 2; ++ct) {
        f32x4 a = acc[rt][ct];
        a = __builtin_amdgcn_mfma_f32_16x16x32_bf16(amh, bwh[ct], a, 0, 0, 0);
        a = __builtin_amdgcn_mfma_f32_16x16x32_bf16(amh, bwl[ct], a, 0, 0, 0);
        a = __builtin_amdgcn_mfma_f32_16x16x32_bf16(aml, bwh[ct], a, 0, 0, 0);
        a = __builtin_amdgcn_mfma_f32_16x16x32_bf16(ahh, buh[ct], a, 0, 0, 0);
        a = __builtin_amdgcn_mfma_f32_16x16x32_bf16(ahh, bul[ct], a, 0, 0, 0);
        a = __builtin_amdgcn_mfma_f32_16x16x32_bf16(ahl, buh[ct], a, 0, 0, 0);
        acc[rt][ct] = a;
      }
    }
  }

  __syncthreads();
  float fv[4][2][4], hvv[4][2][4];
#pragma unroll
  for (int rt = 0; rt < 4; ++rt)
#pragma unroll
    for (int ct = 0; ct < 2; ++ct) {
      int j = (2 * w + ct) * 16 + lj;
#pragma unroll
      for (int r = 0; r < 4; ++r) {
        int nl = rt * 16 + q * 4 + r;
        float z = acc[rt][ct][r] + bfj[ct];
        float f = sigmoid_f(z);
        int he = nl * LDST + j;
        float hval = (float)hHi[he] + (float)hLo[he];
        float g = f * hval;
        __bf16 ghi = (__bf16)g;
        hHi[he] = ghi;
        hLo[he] = (__bf16)(g - (float)ghi);
        fv[rt][ct][r] = f;
        hvv[rt][ct][r] = hval;
        acc[rt][ct][r] = 0.f;
      }
    }
  __syncthreads();

#pragma unroll
  for (int kc = 0; kc < 128; kc += 32) {
    bf16x8 bwh[2], bwl[2], buh[2], bul[2];
#pragma unroll
    for (int ct = 0; ct < 2; ++ct) {
      int off = ((2 * w + ct) * 16 + lj) * 128 + kc + q * 8;
      bwh[ct] = *(const bf16x8*)&Whi[2 * 16384 + off];
      bwl[ct] = *(const bf16x8*)&Wlo[2 * 16384 + off];
      buh[ct] = *(const bf16x8*)&Whi[3 * 16384 + off];
      bul[ct] = *(const bf16x8*)&Wlo[3 * 16384 + off];
    }
#pragma unroll
    for (int rt = 0; rt < 4; ++rt) {
      int e0 = (rt * 16 + lj) * LDST + kc + q * 8;
      bf16x8 amh = *(const bf16x8*)&mHi[e0];
      bf16x8 aml = *(const bf16x8*)&mLo[e0];
      bf16x8 agh = *(const bf16x8*)&hHi[e0];
      bf16x8 agl = *(const bf16x8*)&hLo[e0];
#pragma unroll
      for (int ct = 0; ct < 2; ++ct) {
        f32x4 a = acc[rt][ct];
        a = __builtin_amdgcn_mfma_f32_16x16x32_bf16(amh, bwh[ct], a, 0, 0, 0);
        a = __builtin_amdgcn_mfma_f32_16x16x32_bf16(amh, bwl[ct], a, 0, 0, 0);
        a = __builtin_amdgcn_mfma_f32_16x16x32_bf16(aml, bwh[ct], a, 0, 0, 0);
        a = __builtin_amdgcn_mfma_f32_16x16x32_bf16(agh, buh[ct], a, 0, 0, 0);
        a = __builtin_amdgcn_mfma_f32_16x16x32_bf16(agh, bul[ct], a, 0, 0, 0);
        a = __builtin_amdgcn_mfma_f32_16x16x32_bf16(agl, buh[ct], a, 0, 0, 0);
        acc[rt][ct] = a;
      }
    }
  }

#pragma unroll
  for (int rt = 0; rt < 4; ++rt)
#pragma unroll
    for (int ct = 0; ct < 2; ++ct) {
      int j = (2 * w + ct) * 16 + lj;
#pragma unroll
      for (int r = 0; r < 4; ++r) {
        float T = tanh_f(acc[rt][ct][r] + bhj[ct]);
        float f = fv[rt][ct][r];
        float hn = (1.f - f) * hvv[rt][ct][r] + f * T;
        h[(nb + rt * 16 + q * 4 + r) * 128 + j] = hn;
      }
    }
}

// ---------------------------------------------------------------------------
// LSTM gates as ONE all-graphs GEMM: gates[128x512] = Scat[128x384] @ Wcat.T
// Scat = [q_star | h_l], split-bf16 MFMA. 16 blocks x 256 thr; block owns a
// 32-col tile; two 64-graph chunks staged in LDS.
// ---------------------------------------------------------------------------
__global__ __launch_bounds__(256) void k_gates(const float* __restrict__ q_star,
                                               const float* __restrict__ h_l,
                                               const __bf16* __restrict__ WcHi,
                                               const __bf16* __restrict__ WcLo,
                                               float* __restrict__ gates) {
  __shared__ __bf16 sHi[64 * KPAD], sLo[64 * KPAD];
  const int t = threadIdx.x, b = blockIdx.x;
  const int w = t >> 6, l = t & 63, lj = l & 15, q = l >> 4;
  const int ct = b * 2 + (w & 1);   // global col-tile (j base = ct*16)
  const int rh = w >> 1;            // row-half within 64-graph chunk
  const float4* qs4 = (const float4*)q_star;
  const float4* hl4 = (const float4*)h_l;
  const int sg = t >> 2, part = t & 3;   // staging: 4 threads per state row

  for (int chunk = 0; chunk < 2; ++chunk) {
    __syncthreads();
    int g0 = chunk * 64;
#pragma unroll
    for (int i = 0; i < 24; ++i) {
      int k4 = part * 24 + i;  // 0..95 float4 within Scat row
      float4 v = (k4 < 64) ? qs4[(g0 + sg) * 64 + k4]
                           : hl4[(g0 + sg) * 32 + (k4 - 64)];
      bf16x4 hi, lo;
      hi[0] = (__bf16)v.x; lo[0] = (__bf16)(v.x - (float)hi[0]);
      hi[1] = (__bf16)v.y; lo[1] = (__bf16)(v.y - (float)hi[1]);
      hi[2] = (__bf16)v.z; lo[2] = (__bf16)(v.z - (float)hi[2]);
      hi[3] = (__bf16)v.w; lo[3] = (__bf16)(v.w - (float)hi[3]);
      int e0 = sg * KPAD + k4 * 4;
      *(bf16x4*)&sHi[e0] = hi; *(bf16x4*)&sLo[e0] = lo;
    }
    __syncthreads();
    f32x4 acc[2] = {};
#pragma unroll
    for (int kc = 0; kc < KCAT; kc += 32) {
      bf16x8 bh = *(const bf16x8*)&WcHi[(ct * 16 + lj) * KCAT + kc + q * 8];
      bf16x8 bl = *(const bf16x8*)&WcLo[(ct * 16 + lj) * KCAT + kc + q * 8];
#pragma unroll
      for (int rt = 0; rt < 2; ++rt) {
        int e0 = ((rh * 2 + rt) * 16 + lj) * KPAD + kc + q * 8;
        bf16x8 ah = *(const bf16x8*)&sHi[e0];
        bf16x8 al = *(const bf16x8*)&sLo[e0];
        f32x4 a = acc[rt];
        a = __builtin_amdgcn_mfma_f32_16x16x32_bf16(ah, bh, a, 0, 0, 0);
        a = __builtin_amdgcn_mfma_f32_16x16x32_bf16(ah, bl, a, 0, 0, 0);
        a = __builtin_amdgcn_mfma_f32_16x16x32_bf16(al, bh, a, 0, 0, 0);
        acc[rt] = a;
      }
    }
    int j = ct * 16 + lj;
#pragma unroll
    for (int rt = 0; rt < 2; ++rt)
#pragma unroll
      for (int r = 0; r < 4; ++r) {
        int g = g0 + (rh * 2 + rt) * 16 + q * 4 + r;
        gates[g * 512 + j] = acc[rt][r];
      }
  }
}

// LSTM cell update (elementwise): c,h from gates; writes q part of q_star
__global__ __launch_bounds__(256) void k_cell(const float* __restrict__ gates,
                                              const float* __restrict__ b_ih,
                                              const float* __restrict__ b_hh,
                                              float* __restrict__ q_star,
                                              float* __restrict__ h_l,
                                              float* __restrict__ c_l) {
  int id = blockIdx.x * 256 + threadIdx.x;  // 16384
  int g = id >> 7, hu = id & 127;
  float gi = gates[g * 512 + hu]       + b_ih[hu]       + b_hh[hu];
  float gf = gates[g * 512 + 128 + hu] + b_ih[128 + hu] + b_hh[128 + hu];
  float gg = gates[g * 512 + 256 + hu] + b_ih[256 + hu] + b_hh[256 + hu];
  float go = gates[g * 512 + 384 + hu] + b_ih[384 + hu] + b_hh[384 + hu];
  float c = sigmoid_f(gf) * c_l[id] + sigmoid_f(gi) * tanh_f(gg);
  float hh = sigmoid_f(go) * tanh_f(c);
  c_l[id] = c;
  h_l[id] = hh;
  q_star[g * 256 + hu] = hh;
}

// ---------------------------------------------------------------------------
// Flash attention per graph: r = softmax(<h,q>) @ h ; writes r into q_star.
// One block/graph, 1024 threads = 32 half-wave streams, 2 nodes in flight.
// ---------------------------------------------------------------------------
__global__ __launch_bounds__(1024) void k_attn(const float* __restrict__ h,
                                               const int* __restrict__ batch,
                                               float* __restrict__ q_star) {
  const int g = blockIdx.x, t = threadIdx.x;
  const int w = t >> 6, l = t & 63;
  const int half = l >> 5, li = l & 31;
  const int hw = 2 * w + half;
  __shared__ float redM[32], redS[32], scl[32];
  __shared__ float rPart[32][132];
  __shared__ float gInvS;
  __shared__ int bnd[2];

  if (t < 2) {
    int tgt = g + t;
    int lo = 0, hi = N_NODES;
    while (lo < hi) { int mid = (lo + hi) >> 1; if (batch[mid] < tgt) lo = mid + 1; else hi = mid; }
    bnd[t] = lo;
  }
  __syncthreads();
  const int s0 = bnd[0], s1 = bnd[1];

  float4 qv = ((const float4*)q_star)[g * 64 + li];  // q part, lane's 4 dims
  const float q0 = qv.x, q1 = qv.y, q2 = qv.z, q3 = qv.w;

  float mw = -INFINITY, sw = 0.f;
  float4 racc = {0.f, 0.f, 0.f, 0.f};
  const float4* h4 = (const float4*)h;
  int n = s0 + hw;
  for (; n + 32 < s1; n += 64) {
    float4 hv0 = h4[n * 32 + li];
    float4 hv1 = h4[(n + 32) * 32 + li];
    float v0 = hv0.x * q0 + hv0.y * q1 + hv0.z * q2 + hv0.w * q3;
    float v1 = hv1.x * q0 + hv1.y * q1 + hv1.z * q2 + hv1.w * q3;
#pragma unroll
    for (int o = 16; o > 0; o >>= 1) {
      v0 += __shfl_xor(v0, o, 64);
      v1 += __shfl_xor(v1, o, 64);
    }
    float nm = fmaxf(mw, fmaxf(v0, v1));
    float sc = __expf(mw - nm);
    float w0 = __expf(v0 - nm);
    float w1 = __expf(v1 - nm);
    sw = sw * sc + w0 + w1;
    racc.x = racc.x * sc + w0 * hv0.x + w1 * hv1.x;
    racc.y = racc.y * sc + w0 * hv0.y + w1 * hv1.y;
    racc.z = racc.z * sc + w0 * hv0.z + w1 * hv1.z;
    racc.w = racc.w * sc + w0 * hv0.w + w1 * hv1.w;
    mw = nm;
  }
  for (; n < s1; n += 32) {
    float4 hv = h4[n * 32 + li];
    float v = hv.x * q0 + hv.y * q1 + hv.z * q2 + hv.w * q3;
#pragma unroll
    for (int o = 16; o > 0; o >>= 1) v += __shfl_xor(v, o, 64);
    float nm = fmaxf(mw, v);
    float sc = __expf(mw - nm);
    float wg = __expf(v - nm);
    sw = sw * sc + wg;
    racc.x = racc.x * sc + wg * hv.x;
    racc.y = racc.y * sc + wg * hv.y;
    racc.z = racc.z * sc + wg * hv.z;
    racc.w = racc.w * sc + wg * hv.w;
    mw = nm;
  }
  if (li == 0) { redM[hw] = mw; redS[hw] = sw; }
  *(float4*)&rPart[hw][4 * li] = racc;
  __syncthreads();
  if (t == 0) {
    float M = -INFINITY;
    for (int i = 0; i < 32; ++i) M = fmaxf(M, redM[i]);
    float S = 0.f;
    for (int i = 0; i < 32; ++i) {
      float s_ = (redM[i] > -INFINITY && M > -INFINITY) ? __expf(redM[i] - M) : 0.f;
      scl[i] = s_;
      S += redS[i] * s_;
    }
    gInvS = (S > 0.f) ? __fdividef(1.f, S) : 0.f;
  }
  __syncthreads();
  if (t < 128) {
    float inv = gInvS;
    float r = 0.f;
#pragma unroll
    for (int i = 0; i < 32; ++i) r += rPart[i][t] * scl[i];
    q_star[g * 256 + 128 + t] = r * inv;
  }
}

// prediction: out[g] = <q_star[g], W_pred> + b
__global__ void k_pred(const float* __restrict__ q_star, const float* __restrict__ Wp,
                       const float* __restrict__ bp, float* __restrict__ out) {
  int g = threadIdx.x;  // 128
  float s = 0.f;
  for (int k = 0; k < 256; ++k) s += q_star[g * 256 + k] * Wp[k];
  out[g] = s + bp[0];
}

// ---------------------------------------------------------------------------
extern "C" void kernel_launch(void* const* d_in, const int* in_sizes, int n_in,
                              void* d_out, int out_size, void* d_ws, size_t ws_size,
                              hipStream_t stream) {
  const float* x      = (const float*)d_in[0];
  const int*   ei     = (const int*)d_in[1];
  const int*   batch  = (const int*)d_in[2];
  const float* W_in   = (const float*)d_in[3];
  const float* b_in   = (const float*)d_in[4];
  const float* W_f    = (const float*)d_in[5];
  const float* U_f    = (const float*)d_in[6];
  const float* b_f    = (const float*)d_in[7];
  const float* W_h    = (const float*)d_in[8];
  const float* U_h    = (const float*)d_in[9];
  const float* b_h    = (const float*)d_in[10];
  const float* w_ih   = (const float*)d_in[11];
  const float* w_hh   = (const float*)d_in[12];
  const float* b_ih   = (const float*)d_in[13];
  const float* b_hh   = (const float*)d_in[14];
  const float* W_pred = (const float*)d_in[15];
  const float* b_pred = (const float*)d_in[16];
  float* out = (float*)d_out;

  char* ws = (char*)d_ws;
  float* h      = (float*)(ws);                    // 51,200,000 B
  float* m      = (float*)(ws + 51200000);         // 51,200,000 B [MPNN only]
  int*   rowstart = (int*)(ws + 103063808);        //    400,016 B
  int*   srcSorted= (int*)(ws + 103463824);        //  2,560,000 B
  int*   bsum   = (int*)  (ws + 106023824);        //        112 B
  int*   boff   = (int*)  (ws + 106023936);        //        112 B
  // region at +102,400,000 (400,000 B): deg/cursor (CSR build) then Whi/Wlo
  int*    deg    = (int*)(ws + 102400000);
  int*    cursor = (int*)(ws + 102400000);
  __bf16* Whi    = (__bf16*)(ws + 102400000);      //    131,072 B
  __bf16* Wlo    = (__bf16*)(ws + 102531072);      //    131,072 B
  // set2set buffers alias the (dead after MPNN) m region:
  char* mB = (char*)m;
  __bf16* WcHi   = (__bf16*)(mB);                  //    393,216 B
  __bf16* WcLo   = (__bf16*)(mB + 393216);         //    393,216 B
  float*  gates  = (float*)(mB + 786432);          //    262,144 B
  float*  q_star = (float*)(mB + 1048576);         //    131,072 B
  float*  h_l    = (float*)(mB + 1179648);         //     65,536 B
  float*  c_l    = (float*)(mB + 1245184);         //     65,536 B

  const int* src = ei;
  const int* dst = ei + N_EDGES;

  // ---- CSR build (once; reused by all 3 MPNN steps) ----
  hipMemsetAsync(deg, 0, N_NODES * 4, stream);
  k_hist<<<(N_EDGES + 255) / 256, 256, 0, stream>>>(dst, deg);
  k_scan_part<<<SCAN_NB, 256, 0, stream>>>(deg, bsum);
  k_scan_mid<<<1, 32, 0, stream>>>(bsum, boff, rowstart);
  k_scan_final<<<SCAN_NB, 256, 0, stream>>>(deg, boff, rowstart);
  hipMemcpyAsync(cursor, rowstart, N_NODES * 4, hipMemcpyDeviceToDevice, stream);
  k_fill<<<(N_EDGES + 255) / 256, 256, 0, stream>>>(src, dst, cursor, srcSorted);

  // ---- one-time MGU weight bf16 hi/lo split ----
  k_wsplit<<<256, 256, 0, stream>>>(W_f, U_f, W_h, U_h, Whi, Wlo);

  k_input<<<N_NODES / 32, 256, 0, stream>>>(x, W_in, b_in, h);

  for (int step = 0; step < 3; ++step) {
    k_gather<<<(N_NODES + 7) / 8, 256, 0, stream>>>(h, rowstart, srcSorted, m);
    k_mgu<<<(N_NODES + 63) / 64, 256, 0, stream>>>(h, m, Whi, Wlo, b_f, b_h);
  }

  // ---- Set2Set (m region is dead now; set2set buffers live there) ----
  k_wsplit2<<<512, KCAT, 0, stream>>>(w_ih, w_hh, WcHi, WcLo);
  hipMemsetAsync(q_star, 0, 262144, stream);  // q_star + h_l + c_l contiguous

  for (int s = 0; s < 3; ++s) {
    k_gates<<<16, 256, 0, stream>>>(q_star, h_l, WcHi, WcLo, gates);
    k_cell<<<64, 256, 0, stream>>>(gates, b_ih, b_hh, q_star, h_l, c_l);
    k_attn<<<NGRAPH, 1024, 0, stream>>>(h, batch, q_star);
  }

  k_pred<<<1, 128, 0, stream>>>(q_star, W_pred, b_pred, out);
}